// Round 3
// baseline (356.199 us; speedup 1.0000x reference)
//
#include <hip/hip_runtime.h>

// Problem constants (fixed by setup_inputs: weight (2304,1280) -> G=48, D=1280).
#define G_GRID 48
#define D_DIM  1280
#define MERGE  2
// float4 per output row
#define ROW_F4 (D_DIM / 4)          // 320
#define F4_PER_LANE (ROW_F4 / 64)   // 5

__global__ __launch_bounds__(256)
void pos_embed_bilerp_kernel(const float* __restrict__ weight,   // [G*G, D]
                             const int*   __restrict__ grid_thw, // [n, 3]
                             float*       __restrict__ out,      // [total_rows, D]
                             int n_grid)
{
    const int lane = threadIdx.x & 63;
    const int grp  = threadIdx.x >> 6;     // 0..3 -> output row within 2x2 merge block
    const int hi   = grp >> 1;
    const int wi   = grp & 1;

    // total work = sum over entries of (h/2)*(w/2) merge blocks
    long total = 0;
    for (int i = 0; i < n_grid; ++i) {
        int h = grid_thw[3 * i + 1];
        int w = grid_thw[3 * i + 2];
        total += (long)(h / MERGE) * (w / MERGE);
    }

    for (long wid0 = blockIdx.x; wid0 < total; wid0 += gridDim.x) {
        // locate grid entry for this work id
        long wid = wid0;
        long row_off = 0;
        int T = 0, H = 0, W = 0;
        for (int i = 0; i < n_grid; ++i) {
            int t = grid_thw[3 * i + 0];
            int h = grid_thw[3 * i + 1];
            int w = grid_thw[3 * i + 2];
            long nb = (long)(h / MERGE) * (w / MERGE);
            if (wid < nb) { T = t; H = h; W = w; break; }
            wid -= nb;
            row_off += (long)t * h * w;
        }

        const int Wb = W / MERGE;
        const int hb = (int)(wid / Wb);
        const int wb = (int)(wid % Wb);
        const int hpos = hb * MERGE + hi;
        const int wpos = wb * MERGE + wi;

        // linspace(0, G-1, n): idx[i] = i * (G-1)/(n-1), f32; floor by trunc; ceil clipped
        const float sh = (H > 1) ? (float)(G_GRID - 1) / (float)(H - 1) : 0.0f;
        const float sw = (W > 1) ? (float)(G_GRID - 1) / (float)(W - 1) : 0.0f;
        const float fh = sh * (float)hpos;
        const float fw = sw * (float)wpos;
        int hf = (int)fh;
        int wf = (int)fw;
        int hc = min(hf + 1, G_GRID - 1);
        int wc = min(wf + 1, G_GRID - 1);
        const float dh = fh - (float)hf;
        const float dw = fw - (float)wf;
        const float w00 = (1.0f - dh) * (1.0f - dw);
        const float w01 = (1.0f - dh) * dw;
        const float w10 = dh * (1.0f - dw);
        const float w11 = dh * dw;

        const float4* __restrict__ r00 = (const float4*)(weight + (long)(hf * G_GRID + wf) * D_DIM);
        const float4* __restrict__ r01 = (const float4*)(weight + (long)(hf * G_GRID + wc) * D_DIM);
        const float4* __restrict__ r10 = (const float4*)(weight + (long)(hc * G_GRID + wf) * D_DIM);
        const float4* __restrict__ r11 = (const float4*)(weight + (long)(hc * G_GRID + wc) * D_DIM);

        float4 vals[F4_PER_LANE];
#pragma unroll
        for (int j = 0; j < F4_PER_LANE; ++j) {
            const int d4 = j * 64 + lane;   // coalesced: consecutive lanes -> consecutive float4
            float4 a = r00[d4];
            float4 b = r01[d4];
            float4 c = r10[d4];
            float4 d = r11[d4];
            float4 v;
            v.x = w00 * a.x + w01 * b.x + w10 * c.x + w11 * d.x;
            v.y = w00 * a.y + w01 * b.y + w10 * c.y + w11 * d.y;
            v.z = w00 * a.z + w01 * b.z + w10 * c.z + w11 * d.z;
            v.w = w00 * a.w + w01 * b.w + w10 * c.w + w11 * d.w;
            vals[j] = v;
        }

        // write the same interpolated row for every t (pure repeat), at merge-permuted rows
        for (int ti = 0; ti < T; ++ti) {
            const long orow = row_off
                            + (((long)ti * (H / MERGE) + hb) * Wb + wb) * (MERGE * MERGE)
                            + grp;
            float4* __restrict__ o = (float4*)(out + orow * D_DIM);
#pragma unroll
            for (int j = 0; j < F4_PER_LANE; ++j) {
                o[j * 64 + lane] = vals[j];
            }
        }
    }
}

extern "C" void kernel_launch(void* const* d_in, const int* in_sizes, int n_in,
                              void* d_out, int out_size, void* d_ws, size_t ws_size,
                              hipStream_t stream) {
    const float* weight   = (const float*)d_in[0];
    const int*   grid_thw = (const int*)d_in[1];
    float*       out      = (float*)d_out;
    const int n_grid = in_sizes[1] / 3;

    // grid-stride kernel; 8192 blocks covers the nominal 8*(32*32) merge blocks exactly
    const int blocks = 8192;
    hipLaunchKernelGGL(pos_embed_bilerp_kernel, dim3(blocks), dim3(256), 0, stream,
                       weight, grid_thw, out, n_grid);
}